// Round 1
// baseline (447.727 us; speedup 1.0000x reference)
//
#include <hip/hip_runtime.h>
#include <cstdint>
#include <cstddef>

#define DM 1024
#define NH 16
#define DQ 64
#define NB 8
#define LSEQ 1024
#define NEGV -4294967295.0f

typedef __attribute__((ext_vector_type(8))) short short8;
typedef __attribute__((ext_vector_type(4))) float floatx4;

__device__ __forceinline__ unsigned short f2bf(float f) {
  union { float f; unsigned u; } v; v.f = f;
  unsigned r = v.u + 0x7FFFu + ((v.u >> 16) & 1u);
  return (unsigned short)(r >> 16);
}
__device__ __forceinline__ float bf2f(unsigned short u) {
  union { unsigned u; float f; } v; v.u = ((unsigned)u) << 16;
  return v.f;
}

__device__ __forceinline__ void async_load16(const void* g, void* l) {
  __builtin_amdgcn_global_load_lds(
      (const __attribute__((address_space(1))) unsigned int*)g,
      (__attribute__((address_space(3))) unsigned int*)l, 16, 0, 0);
}

// ---------------- convert q,k (f32 -> bf16) ----------------
__global__ void convert_qk(const float* __restrict__ q, const float* __restrict__ k,
                           unsigned short* __restrict__ qb, unsigned short* __restrict__ kb) {
  size_t i = ((size_t)blockIdx.x * 256 + threadIdx.x) * 4;
  float4 a = *(const float4*)&q[i];
  ushort4 r;
  r.x = f2bf(a.x); r.y = f2bf(a.y); r.z = f2bf(a.z); r.w = f2bf(a.w);
  *(ushort4*)&qb[i] = r;
  float4 b = *(const float4*)&k[i];
  ushort4 s;
  s.x = f2bf(b.x); s.y = f2bf(b.y); s.z = f2bf(b.z); s.w = f2bf(b.w);
  *(ushort4*)&kb[i] = s;
}

// ---------------- transpose W (f32 [K][N]) -> Wt (bf16 [N][K]) ----------------
__global__ void transpose_w(const float* __restrict__ Wq, const float* __restrict__ Wk,
                            const float* __restrict__ Wv, unsigned short* __restrict__ Wt) {
  int z = blockIdx.z;
  const float* W = (z == 0) ? Wq : (z == 1) ? Wk : Wv;
  __shared__ float tile[32][33];
  int n0 = blockIdx.x * 32, k0 = blockIdx.y * 32;
  int tx = threadIdx.x;
  for (int j = threadIdx.y; j < 32; j += 8)
    tile[j][tx] = W[(size_t)(k0 + j) * DM + n0 + tx];
  __syncthreads();
  unsigned short* o = Wt + (size_t)z * DM * DM;
  for (int j = threadIdx.y; j < 32; j += 8)
    o[(size_t)(n0 + j) * DM + k0 + tx] = f2bf(tile[tx][j]);
}

// ---------------- projection GEMM: P = X @ W + b, bf16 MFMA, m97-style ----------------
// A: [8192][1024] bf16 row-major (qb or kb). Bt: [1024 n][1024 k] bf16.
// Output layout: P[b][h][l][d] bf16, row m = b*L + l, col n = h*64 + d.
__global__ __launch_bounds__(256) void gemm_proj(
    const unsigned short* __restrict__ qb, const unsigned short* __restrict__ kb,
    const unsigned short* __restrict__ Wt,
    const float* __restrict__ bq, const float* __restrict__ bk, const float* __restrict__ bv,
    unsigned short* __restrict__ Pq, unsigned short* __restrict__ Pk, unsigned short* __restrict__ Pv) {
  const int z = blockIdx.z;
  const unsigned short* A = (z == 0) ? qb : kb;
  const unsigned short* Bt = Wt + (size_t)z * DM * DM;
  const float* bias = (z == 0) ? bq : (z == 1) ? bk : bv;
  unsigned short* P = (z == 0) ? Pq : (z == 1) ? Pk : Pv;

  __shared__ unsigned short As[128 * 32];
  __shared__ unsigned short Bs[128 * 32];

  const int tid = threadIdx.x;
  const int lane = tid & 63;
  const int wave = tid >> 6;
  const int l16 = lane & 15, quad = lane >> 4;
  const int wm = wave & 1, wn = wave >> 1;
  const int rowBase = blockIdx.y * 128;
  const int colBase = blockIdx.x * 128;

  floatx4 acc[4][4];
  const floatx4 zf = {0.f, 0.f, 0.f, 0.f};
#pragma unroll
  for (int i = 0; i < 4; i++)
#pragma unroll
    for (int j = 0; j < 4; j++) acc[i][j] = zf;

  for (int kt = 0; kt < DM; kt += 32) {
    // stage A,B tiles: 8 chunks each of 1024B; wave w does chunks {w, w+4}
#pragma unroll
    for (int c = wave; c < 8; c += 4) {
      const unsigned short* ga = A + (size_t)(rowBase + c * 16 + (lane >> 2)) * DM + kt + (lane & 3) * 8;
      async_load16(ga, &As[c * 512]);
      const unsigned short* gb = Bt + (size_t)(colBase + c * 16 + (lane >> 2)) * DM + kt + (lane & 3) * 8;
      async_load16(gb, &Bs[c * 512]);
    }
    __syncthreads();

    short8 af[4], bfr[4];
#pragma unroll
    for (int i = 0; i < 4; i++)
      af[i] = *(const short8*)&As[(wm * 64 + i * 16 + l16) * 32 + quad * 8];
#pragma unroll
    for (int j = 0; j < 4; j++)
      bfr[j] = *(const short8*)&Bs[(wn * 64 + j * 16 + l16) * 32 + quad * 8];
#pragma unroll
    for (int i = 0; i < 4; i++)
#pragma unroll
      for (int j = 0; j < 4; j++)
        acc[i][j] = __builtin_amdgcn_mfma_f32_16x16x32_bf16(af[i], bfr[j], acc[i][j], 0, 0, 0);
    __syncthreads();
  }

  // epilogue: bias + scatter to [b][h][l][d]
#pragma unroll
  for (int j = 0; j < 4; j++) {
    const int col = colBase + wn * 64 + j * 16 + l16;
    const float bv_ = bias[col];
    const int h = col >> 6, d = col & 63;
#pragma unroll
    for (int i = 0; i < 4; i++) {
      const int row0 = rowBase + wm * 64 + i * 16 + quad * 4;
#pragma unroll
      for (int r = 0; r < 4; r++) {
        const int rr = row0 + r;
        const int b = rr >> 10, l = rr & 1023;
        P[((size_t)(b * NH + h) * LSEQ + l) * DQ + d] = f2bf(acc[i][j][r] + bv_);
      }
    }
  }
}

// ---------------- masks: sign(|sum_d proj|) per (b,h,l) ----------------
__global__ void mask_kernel(const unsigned short* __restrict__ Pq, const unsigned short* __restrict__ Pk,
                            float* __restrict__ qmask, float* __restrict__ kmask) {
  const int r = blockIdx.x * 256 + threadIdx.x;  // 0..131071
  float sq = 0.f, sk = 0.f;
  const unsigned short* pq = Pq + (size_t)r * DQ;
  const unsigned short* pk = Pk + (size_t)r * DQ;
#pragma unroll
  for (int e = 0; e < DQ; e++) { sq += bf2f(pq[e]); sk += bf2f(pk[e]); }
  qmask[r] = (sq != 0.f) ? 1.f : 0.f;
  kmask[r] = (sk != 0.f) ? 1.f : 0.f;
}

// ---------------- flash attention (causal + key/query masks) ----------------
// grid: (L/64 q-blocks, B*H). block 256 = 4 waves, wave w owns q rows qb*64+w*16..+15.
__global__ __launch_bounds__(256) void attn_kernel(
    const unsigned short* __restrict__ Q, const unsigned short* __restrict__ K,
    const unsigned short* __restrict__ V,
    const float* __restrict__ kmask, const float* __restrict__ qmask,
    const float* __restrict__ qin, float* __restrict__ out) {
  const int qblk = blockIdx.x;
  const int bh = blockIdx.y;
  const int b = bh >> 4, h = bh & 15;
  const size_t base = (size_t)bh * LSEQ * DQ;

  const int tid = threadIdx.x;
  const int lane = tid & 63;
  const int wave = tid >> 6;
  const int l16 = lane & 15, quad = lane >> 4;
  const int q0 = qblk * 64 + wave * 16;

  __shared__ unsigned short Ks[32 * 72];      // key tile, row stride 72 (pad)
  __shared__ unsigned short Vt[64 * 40];      // V transposed [d][key], stride 40
  __shared__ unsigned short Ps[4 * 16 * 40];  // per-wave P, stride 40

  // Q fragments (A layout), pre-scaled by 1/8 (exact in bf16)
  short8 qf[2];
#pragma unroll
  for (int c = 0; c < 2; c++) {
    short8 t = *(const short8*)&Q[base + (size_t)(q0 + l16) * DQ + c * 32 + quad * 8];
#pragma unroll
    for (int e = 0; e < 8; e++) {
      float f = bf2f((unsigned short)t[e]) * 0.125f;
      t[e] = (short)f2bf(f);
    }
    qf[c] = t;
  }

  const floatx4 zf = {0.f, 0.f, 0.f, 0.f};
  floatx4 o[4] = {zf, zf, zf, zf};
  float m_r[4] = {-1e30f, -1e30f, -1e30f, -1e30f};
  float l_r[4] = {0.f, 0.f, 0.f, 0.f};

  const int ktiles = qblk * 2 + 2;  // causal: keys up to qblk*64+63
  for (int t = 0; t < ktiles; t++) {
    const int k0 = t * 32;
    // ---- stage K tile + V tile (transposed) ----
    {
      const int rr = tid >> 3;
      const int cc = (tid & 7) * 8;
      *(int4*)&Ks[rr * 72 + cc] = *(const int4*)&K[base + (size_t)(k0 + rr) * DQ + cc];
      int4 vv = *(const int4*)&V[base + (size_t)(k0 + rr) * DQ + cc];
      const unsigned short* vs = (const unsigned short*)&vv;
#pragma unroll
      for (int e = 0; e < 8; e++) Vt[(cc + e) * 40 + rr] = vs[e];
    }
    __syncthreads();

    // ---- S = Q K^T (scaled) ----
    floatx4 s0 = zf, s1 = zf;
    {
      short8 kf;
      kf = *(const short8*)&Ks[l16 * 72 + quad * 8];
      s0 = __builtin_amdgcn_mfma_f32_16x16x32_bf16(qf[0], kf, s0, 0, 0, 0);
      kf = *(const short8*)&Ks[l16 * 72 + 32 + quad * 8];
      s0 = __builtin_amdgcn_mfma_f32_16x16x32_bf16(qf[1], kf, s0, 0, 0, 0);
      kf = *(const short8*)&Ks[(16 + l16) * 72 + quad * 8];
      s1 = __builtin_amdgcn_mfma_f32_16x16x32_bf16(qf[0], kf, s1, 0, 0, 0);
      kf = *(const short8*)&Ks[(16 + l16) * 72 + 32 + quad * 8];
      s1 = __builtin_amdgcn_mfma_f32_16x16x32_bf16(qf[1], kf, s1, 0, 0, 0);
    }

    // ---- masks ----
    const int col0 = k0 + l16, col1 = k0 + 16 + l16;
    const float km0 = kmask[(size_t)bh * LSEQ + col0];
    const float km1 = kmask[(size_t)bh * LSEQ + col1];
#pragma unroll
    for (int r = 0; r < 4; r++) {
      const int row = q0 + quad * 4 + r;
      if (col0 > row || km0 == 0.f) s0[r] = NEGV;
      if (col1 > row || km1 == 0.f) s1[r] = NEGV;
    }

    // ---- online softmax ----
    float mx[4];
#pragma unroll
    for (int r = 0; r < 4; r++) mx[r] = fmaxf(s0[r], s1[r]);
#pragma unroll
    for (int off = 1; off < 16; off <<= 1)
#pragma unroll
      for (int r = 0; r < 4; r++) mx[r] = fmaxf(mx[r], __shfl_xor(mx[r], off));
    float p0[4], p1[4], rs[4], alpha[4];
#pragma unroll
    for (int r = 0; r < 4; r++) {
      const float nm = fmaxf(m_r[r], mx[r]);
      alpha[r] = __expf(m_r[r] - nm);
      m_r[r] = nm;
      p0[r] = __expf(s0[r] - nm);
      p1[r] = __expf(s1[r] - nm);
      rs[r] = p0[r] + p1[r];
    }
#pragma unroll
    for (int off = 1; off < 16; off <<= 1)
#pragma unroll
      for (int r = 0; r < 4; r++) rs[r] += __shfl_xor(rs[r], off);
#pragma unroll
    for (int r = 0; r < 4; r++) l_r[r] = l_r[r] * alpha[r] + rs[r];
#pragma unroll
    for (int j = 0; j < 4; j++)
#pragma unroll
      for (int r = 0; r < 4; r++) o[j][r] *= alpha[r];

    // ---- P -> LDS (C layout -> A layout transpose) ----
    unsigned short* pw = &Ps[wave * 640];
#pragma unroll
    for (int r = 0; r < 4; r++) {
      pw[(quad * 4 + r) * 40 + l16] = f2bf(p0[r]);
      pw[(quad * 4 + r) * 40 + 16 + l16] = f2bf(p1[r]);
    }
    asm volatile("s_waitcnt lgkmcnt(0)" ::: "memory");

    // ---- O += P V ----
    {
      const short8 pf = *(const short8*)&pw[l16 * 40 + quad * 8];
#pragma unroll
      for (int j = 0; j < 4; j++) {
        const short8 vf = *(const short8*)&Vt[(j * 16 + l16) * 40 + quad * 8];
        o[j] = __builtin_amdgcn_mfma_f32_16x16x32_bf16(pf, vf, o[j], 0, 0, 0);
      }
    }
    __syncthreads();
  }

  // ---- epilogue: normalize, query-mask, residual ----
#pragma unroll
  for (int r = 0; r < 4; r++) {
    const int row = q0 + quad * 4 + r;
    const float qm = qmask[(size_t)bh * LSEQ + row];
    const float inv = qm / l_r[r];
#pragma unroll
    for (int j = 0; j < 4; j++) {
      const int d = h * DQ + j * 16 + l16;
      const size_t oi = ((size_t)(b * LSEQ + row)) * DM + d;
      out[oi] = o[j][r] * inv + qin[oi];
    }
  }
}

// ---------------- launch ----------------
extern "C" void kernel_launch(void* const* d_in, const int* in_sizes, int n_in,
                              void* d_out, int out_size, void* d_ws, size_t ws_size,
                              hipStream_t stream) {
  const float* q = (const float*)d_in[0];
  const float* k = (const float*)d_in[1];
  // d_in[2] = subseq_mask (exact causal triu; recomputed in-kernel)
  const float* Wq = (const float*)d_in[3];
  const float* bq = (const float*)d_in[4];
  const float* Wk = (const float*)d_in[5];
  const float* bk = (const float*)d_in[6];
  const float* Wv = (const float*)d_in[7];
  const float* bv = (const float*)d_in[8];
  float* out = (float*)d_out;

  char* w = (char*)d_ws;
  unsigned short* qb = (unsigned short*)(w + 0);          // 16 MB
  unsigned short* kb = (unsigned short*)(w + 16777216);   // 16 MB
  unsigned short* Wt = (unsigned short*)(w + 33554432);   // 6 MB
  unsigned short* Pq = (unsigned short*)(w + 39845888);   // 16 MB
  unsigned short* Pk = (unsigned short*)(w + 56623104);   // 16 MB
  unsigned short* Pv = (unsigned short*)(w + 73400320);   // 16 MB
  float* qmask = (float*)(w + 90177536);                  // 512 KB
  float* kmask = (float*)(w + 90701824);                  // 512 KB

  convert_qk<<<8192, 256, 0, stream>>>(q, k, qb, kb);
  transpose_w<<<dim3(32, 32, 3), dim3(32, 8), 0, stream>>>(Wq, Wk, Wv, Wt);
  gemm_proj<<<dim3(8, 64, 3), 256, 0, stream>>>(qb, kb, Wt, bq, bk, bv, Pq, Pk, Pv);
  mask_kernel<<<512, 256, 0, stream>>>(Pq, Pk, qmask, kmask);
  attn_kernel<<<dim3(16, 128), 256, 0, stream>>>(Pq, Pk, Pv, kmask, qmask, q, out);
}

// Round 2
// 362.775 us; speedup vs baseline: 1.2342x; 1.2342x over previous
//
#include <hip/hip_runtime.h>
#include <cstdint>
#include <cstddef>

#define DM 1024
#define NH 16
#define DQ 64
#define NB 8
#define LSEQ 1024

typedef __attribute__((ext_vector_type(8))) short short8;
typedef __attribute__((ext_vector_type(4))) float floatx4;

__device__ __forceinline__ unsigned short f2bf(float f) {
  union { float f; unsigned u; } v; v.f = f;
  unsigned r = v.u + 0x7FFFu + ((v.u >> 16) & 1u);
  return (unsigned short)(r >> 16);
}
__device__ __forceinline__ float bf2f(unsigned short u) {
  union { unsigned u; float f; } v; v.u = ((unsigned)u) << 16;
  return v.f;
}

__device__ __forceinline__ void async_load16(const void* g, void* l) {
  __builtin_amdgcn_global_load_lds(
      (const __attribute__((address_space(1))) unsigned int*)g,
      (__attribute__((address_space(3))) unsigned int*)l, 16, 0, 0);
}

// ---------------- convert q,k (f32 -> bf16) ----------------
__global__ void convert_qk(const float* __restrict__ q, const float* __restrict__ k,
                           unsigned short* __restrict__ qb, unsigned short* __restrict__ kb) {
  size_t i = ((size_t)blockIdx.x * 256 + threadIdx.x) * 4;
  float4 a = *(const float4*)&q[i];
  ushort4 r;
  r.x = f2bf(a.x); r.y = f2bf(a.y); r.z = f2bf(a.z); r.w = f2bf(a.w);
  *(ushort4*)&qb[i] = r;
  float4 b = *(const float4*)&k[i];
  ushort4 s;
  s.x = f2bf(b.x); s.y = f2bf(b.y); s.z = f2bf(b.z); s.w = f2bf(b.w);
  *(ushort4*)&kb[i] = s;
}

// ---------------- transpose W (f32 [K][N]) -> Wt (bf16 [N][K]) ----------------
__global__ void transpose_w(const float* __restrict__ Wq, const float* __restrict__ Wk,
                            const float* __restrict__ Wv, unsigned short* __restrict__ Wt) {
  int z = blockIdx.z;
  const float* W = (z == 0) ? Wq : (z == 1) ? Wk : Wv;
  __shared__ float tile[32][33];
  int n0 = blockIdx.x * 32, k0 = blockIdx.y * 32;
  int tx = threadIdx.x;
  for (int j = threadIdx.y; j < 32; j += 8)
    tile[j][tx] = W[(size_t)(k0 + j) * DM + n0 + tx];
  __syncthreads();
  unsigned short* o = Wt + (size_t)z * DM * DM;
  for (int j = threadIdx.y; j < 32; j += 8)
    o[(size_t)(n0 + j) * DM + k0 + tx] = f2bf(tile[tx][j]);
}

// ---------------- projection GEMM + fused masks + V-transpose epilogue ----------------
// A: [8192][1024] bf16. Bt: [1024 n][1024 k] bf16.
// z=0 -> Pq [b][h][l][d] + qmask ; z=1 -> Pk [b][h][l][d] + kmask ; z=2 -> Pvt [b][h][d][l]
__global__ __launch_bounds__(256) void gemm_proj(
    const unsigned short* __restrict__ qb, const unsigned short* __restrict__ kb,
    const unsigned short* __restrict__ Wt,
    const float* __restrict__ bq, const float* __restrict__ bk, const float* __restrict__ bv,
    unsigned short* __restrict__ Pq, unsigned short* __restrict__ Pk,
    unsigned short* __restrict__ Pvt,
    float* __restrict__ qmask, float* __restrict__ kmask) {
  const int z = blockIdx.z;
  const unsigned short* A = (z == 0) ? qb : kb;
  const unsigned short* Bt = Wt + (size_t)z * DM * DM;
  const float* bias = (z == 0) ? bq : (z == 1) ? bk : bv;

  __shared__ unsigned short smem[8704];  // As=smem[0:4096], Bs=smem[4096:8192]; epilogue reuses 32x136
  unsigned short* As = smem;
  unsigned short* Bs = smem + 4096;

  const int tid = threadIdx.x;
  const int lane = tid & 63;
  const int wave = tid >> 6;
  const int l16 = lane & 15, quad = lane >> 4;
  const int wm = wave & 1, wn = wave >> 1;
  const int rowBase = blockIdx.y * 128;
  const int colBase = blockIdx.x * 128;

  floatx4 acc[4][4];
  const floatx4 zf = {0.f, 0.f, 0.f, 0.f};
#pragma unroll
  for (int i = 0; i < 4; i++)
#pragma unroll
    for (int j = 0; j < 4; j++) acc[i][j] = zf;

  for (int kt = 0; kt < DM; kt += 32) {
#pragma unroll
    for (int c = wave; c < 8; c += 4) {
      async_load16(A + (size_t)(rowBase + c * 16 + (lane >> 2)) * DM + kt + (lane & 3) * 8, &As[c * 512]);
      async_load16(Bt + (size_t)(colBase + c * 16 + (lane >> 2)) * DM + kt + (lane & 3) * 8, &Bs[c * 512]);
    }
    __syncthreads();

    short8 af[4], bfr[4];
#pragma unroll
    for (int i = 0; i < 4; i++)
      af[i] = *(const short8*)&As[(wm * 64 + i * 16 + l16) * 32 + quad * 8];
#pragma unroll
    for (int j = 0; j < 4; j++)
      bfr[j] = *(const short8*)&Bs[(wn * 64 + j * 16 + l16) * 32 + quad * 8];
#pragma unroll
    for (int i = 0; i < 4; i++)
#pragma unroll
      for (int j = 0; j < 4; j++)
        acc[i][j] = __builtin_amdgcn_mfma_f32_16x16x32_bf16(af[i], bfr[j], acc[i][j], 0, 0, 0);
    __syncthreads();
  }

  // bias add (f32, before any store / mask)
#pragma unroll
  for (int j = 0; j < 4; j++) {
    const float bj = bias[colBase + wn * 64 + j * 16 + l16];
#pragma unroll
    for (int i = 0; i < 4; i++)
#pragma unroll
      for (int r = 0; r < 4; r++) acc[i][j][r] += bj;
  }

  if (z < 2) {
    // fused mask: sign(|sum_d proj|) per (b,h,l); wave wn holds one full head (64 cols)
    float* mask = (z == 0) ? qmask : kmask;
    const int h = (colBase >> 6) + wn;
#pragma unroll
    for (int i = 0; i < 4; i++)
#pragma unroll
      for (int r = 0; r < 4; r++) {
        float rs = acc[i][0][r] + acc[i][1][r] + acc[i][2][r] + acc[i][3][r];
        rs += __shfl_xor(rs, 1);
        rs += __shfl_xor(rs, 2);
        rs += __shfl_xor(rs, 4);
        rs += __shfl_xor(rs, 8);
        if (l16 == 0) {
          const int row = rowBase + wm * 64 + i * 16 + quad * 4 + r;
          mask[((size_t)((row >> 10) * NH + h)) * LSEQ + (row & 1023)] = (rs != 0.f) ? 1.f : 0.f;
        }
      }
    unsigned short* P = (z == 0) ? Pq : Pk;
#pragma unroll
    for (int j = 0; j < 4; j++) {
      const int col = colBase + wn * 64 + j * 16 + l16;
      const int hh = col >> 6, d = col & 63;
#pragma unroll
      for (int i = 0; i < 4; i++) {
        const int row0 = rowBase + wm * 64 + i * 16 + quad * 4;
#pragma unroll
        for (int r = 0; r < 4; r++) {
          const int rr = row0 + r;
          P[((size_t)((rr >> 10) * NH + hh) * LSEQ + (rr & 1023)) * DQ + d] = f2bf(acc[i][j][r]);
        }
      }
    }
  } else {
    // V: transposed store via LDS -> Pvt[b][h][d][l], coalesced 16B global writes
    const int b = rowBase >> 10;
    const int l0r = rowBase & 1023;
#pragma unroll
    for (int j = 0; j < 4; j++) {
      __syncthreads();
#pragma unroll
      for (int i = 0; i < 4; i++) {
        ushort4 v;
        v.x = f2bf(acc[i][j][0]); v.y = f2bf(acc[i][j][1]);
        v.z = f2bf(acc[i][j][2]); v.w = f2bf(acc[i][j][3]);
        *(ushort4*)&smem[(wn * 16 + l16) * 136 + wm * 64 + i * 16 + quad * 4] = v;
      }
      __syncthreads();
      const int c = tid >> 3, seg = tid & 7;
      const int col = colBase + (c >> 4) * 64 + j * 16 + (c & 15);
      const int hh = col >> 6, d = col & 63;
      int4 t0 = *(const int4*)&smem[c * 136 + seg * 16];
      int4 t1 = *(const int4*)&smem[c * 136 + seg * 16 + 8];
      const size_t g = ((size_t)((b * NH + hh) * DQ + d)) * LSEQ + l0r + seg * 16;
      *(int4*)&Pvt[g] = t0;
      *(int4*)&Pvt[g + 8] = t1;
    }
  }
}

// ---------------- flash attention v2: no-max softmax, 64-key tiles, swizzled async staging ----
// grid: (8 q-blocks of 128, B*H). 4 waves; wave w owns q rows qblk*128 + w*32 .. +31.
__global__ __launch_bounds__(256, 4) void attn_kernel(
    const unsigned short* __restrict__ Q, const unsigned short* __restrict__ K,
    const unsigned short* __restrict__ Vt,  // [b][h][d][l]
    const float* __restrict__ kmask, const float* __restrict__ qmask,
    const float* __restrict__ qin, float* __restrict__ out) {
  const int qblk = blockIdx.x;
  const int bh = blockIdx.y;
  const int b = bh >> 4, h = bh & 15;
  const size_t base = (size_t)bh * LSEQ * DQ;

  const int tid = threadIdx.x;
  const int lane = tid & 63;
  const int wave = tid >> 6;
  const int l16 = lane & 15, quad = lane >> 4;
  const int qw = qblk * 128 + wave * 32;

  __shared__ unsigned short Ks[4096];      // 64 keys x 64 d, chunk c ^= (row&7)
  __shared__ unsigned short Vs[4096];      // 64 d x 64 keys, chunk c ^= ((d>>1)&7)
  __shared__ unsigned short Ps[4][2304];   // per-wave P: 32 q x 64 k, stride 72

  // Q fragments, pre-scaled by 1/8 (exact in bf16)
  short8 qf[2][2];
#pragma unroll
  for (int sub = 0; sub < 2; sub++)
#pragma unroll
    for (int c = 0; c < 2; c++) {
      short8 t = *(const short8*)&Q[base + (size_t)(qw + sub * 16 + l16) * DQ + c * 32 + quad * 8];
#pragma unroll
      for (int e = 0; e < 8; e++) t[e] = (short)f2bf(bf2f((unsigned short)t[e]) * 0.125f);
      qf[sub][c] = t;
    }

  const floatx4 zf = {0.f, 0.f, 0.f, 0.f};
  floatx4 o[2][4];
#pragma unroll
  for (int sub = 0; sub < 2; sub++)
#pragma unroll
    for (int jj = 0; jj < 4; jj++) o[sub][jj] = zf;
  float l_p[2][4] = {{0.f, 0.f, 0.f, 0.f}, {0.f, 0.f, 0.f, 0.f}};

  const int swz = (quad ^ (l16 & 7)) * 8;
  const int swz2 = ((quad + 4) ^ (l16 & 7)) * 8;
  const int vswz = (quad ^ (l16 >> 1)) * 8;
  const int vswz2 = ((quad + 4) ^ (l16 >> 1)) * 8;

  const int ktiles = (qblk + 1) * 2;
  for (int t = 0; t < ktiles; t++) {
    const int kt = t * 64;
#pragma unroll
    for (int cc = wave; cc < 8; cc += 4) {
      const int rl = cc * 8 + (lane >> 3);
      const int ck = ((lane & 7) ^ (rl & 7)) * 8;
      async_load16(&K[base + (size_t)(kt + rl) * DQ + ck], &Ks[cc * 512]);
      const int cv = ((lane & 7) ^ ((rl >> 1) & 7)) * 8;
      async_load16(&Vt[base + (size_t)rl * LSEQ + kt + cv], &Vs[cc * 512]);
    }
    __syncthreads();

#pragma unroll
    for (int sub = 0; sub < 2; sub++) {
      floatx4 s[4];
#pragma unroll
      for (int ct = 0; ct < 4; ct++) {
        const int kr = (ct * 16 + l16) * 64;
        const short8 kf0 = *(const short8*)&Ks[kr + swz];
        const short8 kf1 = *(const short8*)&Ks[kr + swz2];
        floatx4 sv = zf;
        sv = __builtin_amdgcn_mfma_f32_16x16x32_bf16(qf[sub][0], kf0, sv, 0, 0, 0);
        sv = __builtin_amdgcn_mfma_f32_16x16x32_bf16(qf[sub][1], kf1, sv, 0, 0, 0);
        s[ct] = sv;
      }
      const int row0 = qw + sub * 16 + quad * 4;
#pragma unroll
      for (int ct = 0; ct < 4; ct++) {
        const int col = kt + ct * 16 + l16;
        const float km = kmask[(size_t)bh * LSEQ + col];
        unsigned short* pr = &Ps[wave][(sub * 16 + quad * 4) * 72 + ct * 16 + l16];
#pragma unroll
        for (int r = 0; r < 4; r++) {
          float e = __expf(s[ct][r]) * km;
          e = (col <= row0 + r) ? e : 0.f;
          l_p[sub][r] += e;
          pr[r * 72] = f2bf(e);
        }
      }
    }
    asm volatile("s_waitcnt lgkmcnt(0)" ::: "memory");

    short8 pf[2][2];
#pragma unroll
    for (int sub = 0; sub < 2; sub++) {
      pf[sub][0] = *(const short8*)&Ps[wave][(sub * 16 + l16) * 72 + quad * 8];
      pf[sub][1] = *(const short8*)&Ps[wave][(sub * 16 + l16) * 72 + 32 + quad * 8];
    }
#pragma unroll
    for (int jj = 0; jj < 4; jj++) {
      const int vr = (jj * 16 + l16) * 64;
      const short8 vf0 = *(const short8*)&Vs[vr + vswz];
      const short8 vf1 = *(const short8*)&Vs[vr + vswz2];
#pragma unroll
      for (int sub = 0; sub < 2; sub++) {
        o[sub][jj] = __builtin_amdgcn_mfma_f32_16x16x32_bf16(pf[sub][0], vf0, o[sub][jj], 0, 0, 0);
        o[sub][jj] = __builtin_amdgcn_mfma_f32_16x16x32_bf16(pf[sub][1], vf1, o[sub][jj], 0, 0, 0);
      }
    }
    __syncthreads();
  }

  // epilogue: one l-reduction, query-mask, residual
  const int hd = h * DQ;
#pragma unroll
  for (int sub = 0; sub < 2; sub++)
#pragma unroll
    for (int r = 0; r < 4; r++) {
      float lv = l_p[sub][r];
      lv += __shfl_xor(lv, 1);
      lv += __shfl_xor(lv, 2);
      lv += __shfl_xor(lv, 4);
      lv += __shfl_xor(lv, 8);
      const int row = qw + sub * 16 + quad * 4 + r;
      const float inv = qmask[(size_t)bh * LSEQ + row] / lv;
#pragma unroll
      for (int jj = 0; jj < 4; jj++) {
        const size_t oi = ((size_t)(b * LSEQ + row)) * DM + hd + jj * 16 + l16;
        out[oi] = o[sub][jj][r] * inv + qin[oi];
      }
    }
}

// ---------------- launch ----------------
extern "C" void kernel_launch(void* const* d_in, const int* in_sizes, int n_in,
                              void* d_out, int out_size, void* d_ws, size_t ws_size,
                              hipStream_t stream) {
  const float* q = (const float*)d_in[0];
  const float* k = (const float*)d_in[1];
  // d_in[2] = subseq_mask (exact causal triu; recomputed in-kernel)
  const float* Wq = (const float*)d_in[3];
  const float* bq = (const float*)d_in[4];
  const float* Wk = (const float*)d_in[5];
  const float* bk = (const float*)d_in[6];
  const float* Wv = (const float*)d_in[7];
  const float* bv = (const float*)d_in[8];
  float* out = (float*)d_out;

  char* w = (char*)d_ws;
  unsigned short* qb = (unsigned short*)(w + 0);          // 16 MB
  unsigned short* kb = (unsigned short*)(w + 16777216);   // 16 MB
  unsigned short* Wt = (unsigned short*)(w + 33554432);   // 6 MB
  unsigned short* Pq = (unsigned short*)(w + 39845888);   // 16 MB
  unsigned short* Pk = (unsigned short*)(w + 56623104);   // 16 MB
  unsigned short* Pvt = (unsigned short*)(w + 73400320);  // 16 MB
  float* qmask = (float*)(w + 90177536);                  // 512 KB
  float* kmask = (float*)(w + 90701824);                  // 512 KB

  convert_qk<<<8192, 256, 0, stream>>>(q, k, qb, kb);
  transpose_w<<<dim3(32, 32, 3), dim3(32, 8), 0, stream>>>(Wq, Wk, Wv, Wt);
  gemm_proj<<<dim3(8, 64, 3), 256, 0, stream>>>(qb, kb, Wt, bq, bk, bv, Pq, Pk, Pvt, qmask, kmask);
  attn_kernel<<<dim3(8, 128), 256, 0, stream>>>(Pq, Pk, Pvt, kmask, qmask, q, out);
}

// Round 3
// 280.928 us; speedup vs baseline: 1.5937x; 1.2913x over previous
//
#include <hip/hip_runtime.h>
#include <cstdint>
#include <cstddef>

#define DM 1024
#define NH 16
#define DQ 64
#define NB 8
#define LSEQ 1024

typedef __attribute__((ext_vector_type(8))) short short8;
typedef __attribute__((ext_vector_type(4))) float floatx4;

__device__ __forceinline__ unsigned short f2bf(float f) {
  union { float f; unsigned u; } v; v.f = f;
  unsigned r = v.u + 0x7FFFu + ((v.u >> 16) & 1u);
  return (unsigned short)(r >> 16);
}
__device__ __forceinline__ float bf2f(unsigned short u) {
  union { unsigned u; float f; } v; v.u = ((unsigned)u) << 16;
  return v.f;
}

__device__ __forceinline__ void async_load16(const void* g, void* l) {
  __builtin_amdgcn_global_load_lds(
      (const __attribute__((address_space(1))) unsigned int*)g,
      (__attribute__((address_space(3))) unsigned int*)l, 16, 0, 0);
}

// ---------------- convert q,k (f32 -> bf16) ----------------
__global__ void convert_qk(const float* __restrict__ q, const float* __restrict__ k,
                           unsigned short* __restrict__ qb, unsigned short* __restrict__ kb) {
  size_t i = ((size_t)blockIdx.x * 256 + threadIdx.x) * 4;
  float4 a = *(const float4*)&q[i];
  ushort4 r;
  r.x = f2bf(a.x); r.y = f2bf(a.y); r.z = f2bf(a.z); r.w = f2bf(a.w);
  *(ushort4*)&qb[i] = r;
  float4 b = *(const float4*)&k[i];
  ushort4 s;
  s.x = f2bf(b.x); s.y = f2bf(b.y); s.z = f2bf(b.z); s.w = f2bf(b.w);
  *(ushort4*)&kb[i] = s;
}

// ---------------- transpose W (f32 [K][N]) -> Wt (bf16 [N][K]) ----------------
__global__ void transpose_w(const float* __restrict__ Wq, const float* __restrict__ Wk,
                            const float* __restrict__ Wv, unsigned short* __restrict__ Wt) {
  int z = blockIdx.z;
  const float* W = (z == 0) ? Wq : (z == 1) ? Wk : Wv;
  __shared__ float tile[32][33];
  int n0 = blockIdx.x * 32, k0 = blockIdx.y * 32;
  int tx = threadIdx.x;
  for (int j = threadIdx.y; j < 32; j += 8)
    tile[j][tx] = W[(size_t)(k0 + j) * DM + n0 + tx];
  __syncthreads();
  unsigned short* o = Wt + (size_t)z * DM * DM;
  for (int j = threadIdx.y; j < 32; j += 8)
    o[(size_t)(n0 + j) * DM + k0 + tx] = f2bf(tile[tx][j]);
}

// ---------------- projection GEMM + fused masks + V-transpose epilogue ----------------
__global__ __launch_bounds__(256) void gemm_proj(
    const unsigned short* __restrict__ qb, const unsigned short* __restrict__ kb,
    const unsigned short* __restrict__ Wt,
    const float* __restrict__ bq, const float* __restrict__ bk, const float* __restrict__ bv,
    unsigned short* __restrict__ Pq, unsigned short* __restrict__ Pk,
    unsigned short* __restrict__ Pvt,
    float* __restrict__ qmask, float* __restrict__ kmask) {
  const int z = blockIdx.z;
  const unsigned short* A = (z == 0) ? qb : kb;
  const unsigned short* Bt = Wt + (size_t)z * DM * DM;
  const float* bias = (z == 0) ? bq : (z == 1) ? bk : bv;

  __shared__ unsigned short smem[8704];
  unsigned short* As = smem;
  unsigned short* Bs = smem + 4096;

  const int tid = threadIdx.x;
  const int lane = tid & 63;
  const int wave = tid >> 6;
  const int l16 = lane & 15, quad = lane >> 4;
  const int wm = wave & 1, wn = wave >> 1;
  const int rowBase = blockIdx.y * 128;
  const int colBase = blockIdx.x * 128;

  floatx4 acc[4][4];
  const floatx4 zf = {0.f, 0.f, 0.f, 0.f};
#pragma unroll
  for (int i = 0; i < 4; i++)
#pragma unroll
    for (int j = 0; j < 4; j++) acc[i][j] = zf;

  for (int kt = 0; kt < DM; kt += 32) {
#pragma unroll
    for (int c = wave; c < 8; c += 4) {
      async_load16(A + (size_t)(rowBase + c * 16 + (lane >> 2)) * DM + kt + (lane & 3) * 8, &As[c * 512]);
      async_load16(Bt + (size_t)(colBase + c * 16 + (lane >> 2)) * DM + kt + (lane & 3) * 8, &Bs[c * 512]);
    }
    __syncthreads();

    short8 af[4], bfr[4];
#pragma unroll
    for (int i = 0; i < 4; i++)
      af[i] = *(const short8*)&As[(wm * 64 + i * 16 + l16) * 32 + quad * 8];
#pragma unroll
    for (int j = 0; j < 4; j++)
      bfr[j] = *(const short8*)&Bs[(wn * 64 + j * 16 + l16) * 32 + quad * 8];
#pragma unroll
    for (int i = 0; i < 4; i++)
#pragma unroll
      for (int j = 0; j < 4; j++)
        acc[i][j] = __builtin_amdgcn_mfma_f32_16x16x32_bf16(af[i], bfr[j], acc[i][j], 0, 0, 0);
    __syncthreads();
  }

#pragma unroll
  for (int j = 0; j < 4; j++) {
    const float bj = bias[colBase + wn * 64 + j * 16 + l16];
#pragma unroll
    for (int i = 0; i < 4; i++)
#pragma unroll
      for (int r = 0; r < 4; r++) acc[i][j][r] += bj;
  }

  if (z < 2) {
    float* mask = (z == 0) ? qmask : kmask;
    const int h = (colBase >> 6) + wn;
#pragma unroll
    for (int i = 0; i < 4; i++)
#pragma unroll
      for (int r = 0; r < 4; r++) {
        float rs = acc[i][0][r] + acc[i][1][r] + acc[i][2][r] + acc[i][3][r];
        rs += __shfl_xor(rs, 1);
        rs += __shfl_xor(rs, 2);
        rs += __shfl_xor(rs, 4);
        rs += __shfl_xor(rs, 8);
        if (l16 == 0) {
          const int row = rowBase + wm * 64 + i * 16 + quad * 4 + r;
          mask[((size_t)((row >> 10) * NH + h)) * LSEQ + (row & 1023)] = (rs != 0.f) ? 1.f : 0.f;
        }
      }
    unsigned short* P = (z == 0) ? Pq : Pk;
#pragma unroll
    for (int j = 0; j < 4; j++) {
      const int col = colBase + wn * 64 + j * 16 + l16;
      const int hh = col >> 6, d = col & 63;
#pragma unroll
      for (int i = 0; i < 4; i++) {
        const int row0 = rowBase + wm * 64 + i * 16 + quad * 4;
#pragma unroll
        for (int r = 0; r < 4; r++) {
          const int rr = row0 + r;
          P[((size_t)((rr >> 10) * NH + hh) * LSEQ + (rr & 1023)) * DQ + d] = f2bf(acc[i][j][r]);
        }
      }
    }
  } else {
    const int b = rowBase >> 10;
    const int l0r = rowBase & 1023;
#pragma unroll
    for (int j = 0; j < 4; j++) {
      __syncthreads();
#pragma unroll
      for (int i = 0; i < 4; i++) {
        ushort4 v;
        v.x = f2bf(acc[i][j][0]); v.y = f2bf(acc[i][j][1]);
        v.z = f2bf(acc[i][j][2]); v.w = f2bf(acc[i][j][3]);
        *(ushort4*)&smem[(wn * 16 + l16) * 136 + wm * 64 + i * 16 + quad * 4] = v;
      }
      __syncthreads();
      const int c = tid >> 3, seg = tid & 7;
      const int col = colBase + (c >> 4) * 64 + j * 16 + (c & 15);
      const int hh = col >> 6, d = col & 63;
      int4 t0 = *(const int4*)&smem[c * 136 + seg * 16];
      int4 t1 = *(const int4*)&smem[c * 136 + seg * 16 + 8];
      const size_t g = ((size_t)((b * NH + hh) * DQ + d)) * LSEQ + l0r + seg * 16;
      *(int4*)&Pvt[g] = t0;
      *(int4*)&Pvt[g + 8] = t1;
    }
  }
}

// ---------------- flash attention v3: dbuf staging, XCD-local bh, causal wave skip ----
// grid: (128 bh, 8 qblk). 4 waves; wave w owns q rows qblk*128 + w*32 .. +31.
__global__ __launch_bounds__(256, 3) void attn_kernel(
    const unsigned short* __restrict__ Q, const unsigned short* __restrict__ K,
    const unsigned short* __restrict__ Vt,  // [b][h][d][l]
    const float* __restrict__ kmask, const float* __restrict__ qmask,
    const float* __restrict__ qin, float* __restrict__ out) {
  const int bh = blockIdx.x;     // fastest -> same bh's qblks share an XCD? no:
  const int qblk = blockIdx.y;   // id = bh + 128*qblk; id%8 = bh%8 -> all qblks of bh same XCD
  const int b = bh >> 4, h = bh & 15;
  const size_t base = (size_t)bh * LSEQ * DQ;

  const int tid = threadIdx.x;
  const int lane = tid & 63;
  const int wave = tid >> 6;
  const int l16 = lane & 15, quad = lane >> 4;
  const int qw = qblk * 128 + wave * 32;

  __shared__ unsigned short Ks[2 * 4096];   // double-buffered 64x64 key tile (swizzled chunks)
  __shared__ unsigned short Vs[2 * 4096];   // double-buffered 64x64 V^T tile
  __shared__ unsigned short Ps[4][2304];    // per-wave P: 32 q x 64 k, stride 72

  short8 qf[2][2];
#pragma unroll
  for (int sub = 0; sub < 2; sub++)
#pragma unroll
    for (int c = 0; c < 2; c++) {
      short8 t = *(const short8*)&Q[base + (size_t)(qw + sub * 16 + l16) * DQ + c * 32 + quad * 8];
#pragma unroll
      for (int e = 0; e < 8; e++) t[e] = (short)f2bf(bf2f((unsigned short)t[e]) * 0.125f);
      qf[sub][c] = t;
    }

  const floatx4 zf = {0.f, 0.f, 0.f, 0.f};
  floatx4 o[2][4];
#pragma unroll
  for (int sub = 0; sub < 2; sub++)
#pragma unroll
    for (int jj = 0; jj < 4; jj++) o[sub][jj] = zf;
  float l_p[2][4] = {{0.f, 0.f, 0.f, 0.f}, {0.f, 0.f, 0.f, 0.f}};

  const int swz = (quad ^ (l16 & 7)) * 8;
  const int swz2 = ((quad + 4) ^ (l16 & 7)) * 8;
  const int vswz = (quad ^ (l16 >> 1)) * 8;
  const int vswz2 = ((quad + 4) ^ (l16 >> 1)) * 8;

  const int srl = (lane >> 3);
  const int ktiles = (qblk + 1) * 2;
  const int tmax = 2 * qblk + (wave >> 1);  // last tile this wave computes; == its diagonal tile

  // stage tile 0 into buffer 0
  {
    const int kt0 = 0;
#pragma unroll
    for (int cc = wave; cc < 8; cc += 4) {
      const int rl = cc * 8 + srl;
      const int ck = ((lane & 7) ^ (rl & 7)) * 8;
      async_load16(&K[base + (size_t)(kt0 + rl) * DQ + ck], &Ks[cc * 512]);
      const int cv = ((lane & 7) ^ ((rl >> 1) & 7)) * 8;
      async_load16(&Vt[base + (size_t)rl * LSEQ + kt0 + cv], &Vs[cc * 512]);
    }
  }
  __syncthreads();

  for (int t = 0; t < ktiles; t++) {
    const int cur = t & 1;
    const int kt = t * 64;
    const bool live = (t <= tmax);

    // kmask prefetch FIRST (so its vmcnt wait doesn't drain the staging queue)
    float km[4];
    if (live) {
#pragma unroll
      for (int ct = 0; ct < 4; ct++) km[ct] = kmask[(size_t)bh * LSEQ + kt + ct * 16 + l16];
    }

    // issue next tile's staging into the other buffer (overlaps this tile's compute)
    if (t + 1 < ktiles) {
      const int nkt = kt + 64;
      const int nb = (cur ^ 1) * 4096;
#pragma unroll
      for (int cc = wave; cc < 8; cc += 4) {
        const int rl = cc * 8 + srl;
        const int ck = ((lane & 7) ^ (rl & 7)) * 8;
        async_load16(&K[base + (size_t)(nkt + rl) * DQ + ck], &Ks[nb + cc * 512]);
        const int cv = ((lane & 7) ^ ((rl >> 1) & 7)) * 8;
        async_load16(&Vt[base + (size_t)rl * LSEQ + nkt + cv], &Vs[nb + cc * 512]);
      }
    }

    if (live) {
      const unsigned short* Kb = &Ks[cur * 4096];
      const unsigned short* Vb = &Vs[cur * 4096];
      const bool diag = (t == tmax);

#pragma unroll
      for (int sub = 0; sub < 2; sub++) {
        floatx4 s[4];
#pragma unroll
        for (int ct = 0; ct < 4; ct++) {
          const int kr = (ct * 16 + l16) * 64;
          const short8 kf0 = *(const short8*)&Kb[kr + swz];
          const short8 kf1 = *(const short8*)&Kb[kr + swz2];
          floatx4 sv = zf;
          sv = __builtin_amdgcn_mfma_f32_16x16x32_bf16(qf[sub][0], kf0, sv, 0, 0, 0);
          sv = __builtin_amdgcn_mfma_f32_16x16x32_bf16(qf[sub][1], kf1, sv, 0, 0, 0);
          s[ct] = sv;
        }
        const int row0 = qw + sub * 16 + quad * 4;
        unsigned short* pw = &Ps[wave][(sub * 16 + quad * 4) * 72];
        if (diag) {
#pragma unroll
          for (int ct = 0; ct < 4; ct++) {
            const int col = kt + ct * 16 + l16;
#pragma unroll
            for (int r = 0; r < 4; r++) {
              float e = __expf(s[ct][r]) * km[ct];
              e = (col <= row0 + r) ? e : 0.f;
              l_p[sub][r] += e;
              pw[r * 72 + ct * 16 + l16] = f2bf(e);
            }
          }
        } else {
#pragma unroll
          for (int ct = 0; ct < 4; ct++) {
#pragma unroll
            for (int r = 0; r < 4; r++) {
              float e = __expf(s[ct][r]) * km[ct];
              l_p[sub][r] += e;
              pw[r * 72 + ct * 16 + l16] = f2bf(e);
            }
          }
        }
      }
      asm volatile("s_waitcnt lgkmcnt(0)" ::: "memory");

      short8 pf[2][2];
#pragma unroll
      for (int sub = 0; sub < 2; sub++) {
        pf[sub][0] = *(const short8*)&Ps[wave][(sub * 16 + l16) * 72 + quad * 8];
        pf[sub][1] = *(const short8*)&Ps[wave][(sub * 16 + l16) * 72 + 32 + quad * 8];
      }
#pragma unroll
      for (int jj = 0; jj < 4; jj++) {
        const int vr = (jj * 16 + l16) * 64;
        const short8 vf0 = *(const short8*)&Vb[vr + vswz];
        const short8 vf1 = *(const short8*)&Vb[vr + vswz2];
#pragma unroll
        for (int sub = 0; sub < 2; sub++) {
          o[sub][jj] = __builtin_amdgcn_mfma_f32_16x16x32_bf16(pf[sub][0], vf0, o[sub][jj], 0, 0, 0);
          o[sub][jj] = __builtin_amdgcn_mfma_f32_16x16x32_bf16(pf[sub][1], vf1, o[sub][jj], 0, 0, 0);
        }
      }
    }
    __syncthreads();  // readies tile t+1 (drains its staging) + protects buffer reuse
  }

  // epilogue: one l-reduction, query-mask, residual
  const int hd = h * DQ;
#pragma unroll
  for (int sub = 0; sub < 2; sub++)
#pragma unroll
    for (int r = 0; r < 4; r++) {
      float lv = l_p[sub][r];
      lv += __shfl_xor(lv, 1);
      lv += __shfl_xor(lv, 2);
      lv += __shfl_xor(lv, 4);
      lv += __shfl_xor(lv, 8);
      const int row = qw + sub * 16 + quad * 4 + r;
      const float inv = qmask[(size_t)bh * LSEQ + row] / lv;
#pragma unroll
      for (int jj = 0; jj < 4; jj++) {
        const size_t oi = ((size_t)(b * LSEQ + row)) * DM + hd + jj * 16 + l16;
        out[oi] = o[sub][jj][r] * inv + qin[oi];
      }
    }
}

// ---------------- launch ----------------
extern "C" void kernel_launch(void* const* d_in, const int* in_sizes, int n_in,
                              void* d_out, int out_size, void* d_ws, size_t ws_size,
                              hipStream_t stream) {
  const float* q = (const float*)d_in[0];
  const float* k = (const float*)d_in[1];
  const float* Wq = (const float*)d_in[3];
  const float* bq = (const float*)d_in[4];
  const float* Wk = (const float*)d_in[5];
  const float* bk = (const float*)d_in[6];
  const float* Wv = (const float*)d_in[7];
  const float* bv = (const float*)d_in[8];
  float* out = (float*)d_out;

  char* w = (char*)d_ws;
  unsigned short* qb = (unsigned short*)(w + 0);
  unsigned short* kb = (unsigned short*)(w + 16777216);
  unsigned short* Wt = (unsigned short*)(w + 33554432);
  unsigned short* Pq = (unsigned short*)(w + 39845888);
  unsigned short* Pk = (unsigned short*)(w + 56623104);
  unsigned short* Pvt = (unsigned short*)(w + 73400320);
  float* qmask = (float*)(w + 90177536);
  float* kmask = (float*)(w + 90701824);

  convert_qk<<<8192, 256, 0, stream>>>(q, k, qb, kb);
  transpose_w<<<dim3(32, 32, 3), dim3(32, 8), 0, stream>>>(Wq, Wk, Wv, Wt);
  gemm_proj<<<dim3(8, 64, 3), 256, 0, stream>>>(qb, kb, Wt, bq, bk, bv, Pq, Pk, Pvt, qmask, kmask);
  attn_kernel<<<dim3(128, 8), 256, 0, stream>>>(Pq, Pk, Pvt, kmask, qmask, q, out);
}

// Round 4
// 252.839 us; speedup vs baseline: 1.7708x; 1.1111x over previous
//
#include <hip/hip_runtime.h>
#include <cstdint>
#include <cstddef>

#define DM 1024
#define NH 16
#define DQ 64
#define NB 8
#define LSEQ 1024

typedef __attribute__((ext_vector_type(8))) short short8;
typedef __attribute__((ext_vector_type(4))) float floatx4;

__device__ __forceinline__ unsigned short f2bf(float f) {
  union { float f; unsigned u; } v; v.f = f;
  unsigned r = v.u + 0x7FFFu + ((v.u >> 16) & 1u);
  return (unsigned short)(r >> 16);
}
__device__ __forceinline__ float bf2f(unsigned short u) {
  union { unsigned u; float f; } v; v.u = ((unsigned)u) << 16;
  return v.f;
}

__device__ __forceinline__ void async_load16(const void* g, void* l) {
  __builtin_amdgcn_global_load_lds(
      (const __attribute__((address_space(1))) unsigned int*)g,
      (__attribute__((address_space(3))) unsigned int*)l, 16, 0, 0);
}

// ---------------- convert q,k (f32 -> bf16) ----------------
__global__ void convert_qk(const float* __restrict__ q, const float* __restrict__ k,
                           unsigned short* __restrict__ qb, unsigned short* __restrict__ kb) {
  size_t i = ((size_t)blockIdx.x * 256 + threadIdx.x) * 4;
  float4 a = *(const float4*)&q[i];
  ushort4 r;
  r.x = f2bf(a.x); r.y = f2bf(a.y); r.z = f2bf(a.z); r.w = f2bf(a.w);
  *(ushort4*)&qb[i] = r;
  float4 b = *(const float4*)&k[i];
  ushort4 s;
  s.x = f2bf(b.x); s.y = f2bf(b.y); s.z = f2bf(b.z); s.w = f2bf(b.w);
  *(ushort4*)&kb[i] = s;
}

// ---------------- transpose W (f32 [K][N]) -> Wt (bf16 [N][K]) ----------------
__global__ void transpose_w(const float* __restrict__ Wq, const float* __restrict__ Wk,
                            const float* __restrict__ Wv, unsigned short* __restrict__ Wt) {
  int z = blockIdx.z;
  const float* W = (z == 0) ? Wq : (z == 1) ? Wk : Wv;
  __shared__ float tile[32][33];
  int n0 = blockIdx.x * 32, k0 = blockIdx.y * 32;
  int tx = threadIdx.x;
  for (int j = threadIdx.y; j < 32; j += 8)
    tile[j][tx] = W[(size_t)(k0 + j) * DM + n0 + tx];
  __syncthreads();
  unsigned short* o = Wt + (size_t)z * DM * DM;
  for (int j = threadIdx.y; j < 32; j += 8)
    o[(size_t)(n0 + j) * DM + k0 + tx] = f2bf(tile[tx][j]);
}

// ---------------- projection GEMM + fused masks + V-transpose epilogue ----------------
// grid (64 row, 8 col, 3): id%8 = row%8 -> all col-blocks of a row-strip share an XCD
// BK=64, XOR-swizzled chunk staging (2-way max on fragment b128 reads)
__global__ __launch_bounds__(256, 4) void gemm_proj(
    const unsigned short* __restrict__ qb, const unsigned short* __restrict__ kb,
    const unsigned short* __restrict__ Wt,
    const float* __restrict__ bq, const float* __restrict__ bk, const float* __restrict__ bv,
    const float* __restrict__ /*unused*/, 
    unsigned short* __restrict__ Pq, unsigned short* __restrict__ Pk,
    unsigned short* __restrict__ Pvt,
    float* __restrict__ qmask, float* __restrict__ kmask) {
  const int z = blockIdx.z;
  const unsigned short* A = (z == 0) ? qb : kb;
  const unsigned short* Bt = Wt + (size_t)z * DM * DM;
  const float* bias = (z == 0) ? bq : (z == 1) ? bk : bv;

  __shared__ unsigned short smem[16384];  // As 128x64, Bs 128x64; epilogue reuses 32x136
  unsigned short* As = smem;
  unsigned short* Bs = smem + 8192;

  const int tid = threadIdx.x;
  const int lane = tid & 63;
  const int wave = tid >> 6;
  const int l16 = lane & 15, quad = lane >> 4;
  const int wm = wave & 1, wn = wave >> 1;
  const int rowBase = blockIdx.x * 128;  // row on x -> XCD locality for A
  const int colBase = blockIdx.y * 128;

  floatx4 acc[4][4];
  const floatx4 zf = {0.f, 0.f, 0.f, 0.f};
#pragma unroll
  for (int i = 0; i < 4; i++)
#pragma unroll
    for (int j = 0; j < 4; j++) acc[i][j] = zf;

  const int srl = lane >> 3;
  const int sl7 = lane & 7;

  for (int kt = 0; kt < DM; kt += 64) {
#pragma unroll
    for (int cc = wave; cc < 16; cc += 4) {
      const int rl = cc * 8 + srl;
      const int ck = (sl7 ^ (rl & 7)) * 8;
      async_load16(A + (size_t)(rowBase + rl) * DM + kt + ck, &As[cc * 512]);
      async_load16(Bt + (size_t)(colBase + rl) * DM + kt + ck, &Bs[cc * 512]);
    }
    __syncthreads();

#pragma unroll
    for (int c = 0; c < 2; c++) {
      const int chnk = ((c << 2) + quad) ^ (l16 & 7);
      short8 af[4], bfr[4];
#pragma unroll
      for (int i = 0; i < 4; i++)
        af[i] = *(const short8*)&As[(wm * 64 + i * 16 + l16) * 64 + chnk * 8];
#pragma unroll
      for (int j = 0; j < 4; j++)
        bfr[j] = *(const short8*)&Bs[(wn * 64 + j * 16 + l16) * 64 + chnk * 8];
#pragma unroll
      for (int i = 0; i < 4; i++)
#pragma unroll
        for (int j = 0; j < 4; j++)
          acc[i][j] = __builtin_amdgcn_mfma_f32_16x16x32_bf16(af[i], bfr[j], acc[i][j], 0, 0, 0);
    }
    __syncthreads();
  }

#pragma unroll
  for (int j = 0; j < 4; j++) {
    const float bj = bias[colBase + wn * 64 + j * 16 + l16];
#pragma unroll
    for (int i = 0; i < 4; i++)
#pragma unroll
      for (int r = 0; r < 4; r++) acc[i][j][r] += bj;
  }

  if (z < 2) {
    float* mask = (z == 0) ? qmask : kmask;
    const int h = (colBase >> 6) + wn;
#pragma unroll
    for (int i = 0; i < 4; i++)
#pragma unroll
      for (int r = 0; r < 4; r++) {
        float rs = acc[i][0][r] + acc[i][1][r] + acc[i][2][r] + acc[i][3][r];
        rs += __shfl_xor(rs, 1);
        rs += __shfl_xor(rs, 2);
        rs += __shfl_xor(rs, 4);
        rs += __shfl_xor(rs, 8);
        if (l16 == 0) {
          const int row = rowBase + wm * 64 + i * 16 + quad * 4 + r;
          mask[((size_t)((row >> 10) * NH + h)) * LSEQ + (row & 1023)] = (rs != 0.f) ? 1.f : 0.f;
        }
      }
    unsigned short* P = (z == 0) ? Pq : Pk;
#pragma unroll
    for (int j = 0; j < 4; j++) {
      const int col = colBase + wn * 64 + j * 16 + l16;
      const int hh = col >> 6, d = col & 63;
#pragma unroll
      for (int i = 0; i < 4; i++) {
        const int row0 = rowBase + wm * 64 + i * 16 + quad * 4;
#pragma unroll
        for (int r = 0; r < 4; r++) {
          const int rr = row0 + r;
          P[((size_t)((rr >> 10) * NH + hh) * LSEQ + (rr & 1023)) * DQ + d] = f2bf(acc[i][j][r]);
        }
      }
    }
  } else {
    const int b = rowBase >> 10;
    const int l0r = rowBase & 1023;
#pragma unroll
    for (int j = 0; j < 4; j++) {
      __syncthreads();
#pragma unroll
      for (int i = 0; i < 4; i++) {
        ushort4 v;
        v.x = f2bf(acc[i][j][0]); v.y = f2bf(acc[i][j][1]);
        v.z = f2bf(acc[i][j][2]); v.w = f2bf(acc[i][j][3]);
        *(ushort4*)&smem[(wn * 16 + l16) * 136 + wm * 64 + i * 16 + quad * 4] = v;
      }
      __syncthreads();
      const int c = tid >> 3, seg = tid & 7;
      const int col = colBase + (c >> 4) * 64 + j * 16 + (c & 15);
      const int hh = col >> 6, d = col & 63;
      int4 t0 = *(const int4*)&smem[c * 136 + seg * 16];
      int4 t1 = *(const int4*)&smem[c * 136 + seg * 16 + 8];
      const size_t g = ((size_t)((b * NH + hh) * DQ + d)) * LSEQ + l0r + seg * 16;
      *(int4*)&Pvt[g] = t0;
      *(int4*)&Pvt[g + 8] = t1;
    }
  }
}

// ---------------- flash attention v4: dbuf, XCD-local bh, heavy-qblk-first ----------------
__global__ __launch_bounds__(256, 4) void attn_kernel(
    const unsigned short* __restrict__ Q, const unsigned short* __restrict__ K,
    const unsigned short* __restrict__ Vt,  // [b][h][d][l]
    const float* __restrict__ kmask, const float* __restrict__ qmask,
    const float* __restrict__ qin, float* __restrict__ out) {
  const int bh = blockIdx.x;          // id%8 = bh%8 -> all qblks of a bh share an XCD
  const int qblk = 7 - blockIdx.y;    // heavy (long) q-blocks launch first -> better tail
  const int b = bh >> 4, h = bh & 15;
  const size_t base = (size_t)bh * LSEQ * DQ;

  const int tid = threadIdx.x;
  const int lane = tid & 63;
  const int wave = tid >> 6;
  const int l16 = lane & 15, quad = lane >> 4;
  const int qw = qblk * 128 + wave * 32;

  __shared__ unsigned short Ks[2 * 4096];
  __shared__ unsigned short Vs[2 * 4096];
  __shared__ unsigned short Ps[4][2304];

  short8 qf[2][2];
#pragma unroll
  for (int sub = 0; sub < 2; sub++)
#pragma unroll
    for (int c = 0; c < 2; c++) {
      short8 t = *(const short8*)&Q[base + (size_t)(qw + sub * 16 + l16) * DQ + c * 32 + quad * 8];
#pragma unroll
      for (int e = 0; e < 8; e++) t[e] = (short)f2bf(bf2f((unsigned short)t[e]) * 0.125f);
      qf[sub][c] = t;
    }

  const floatx4 zf = {0.f, 0.f, 0.f, 0.f};
  floatx4 o[2][4];
#pragma unroll
  for (int sub = 0; sub < 2; sub++)
#pragma unroll
    for (int jj = 0; jj < 4; jj++) o[sub][jj] = zf;
  float l_p[2][4] = {{0.f, 0.f, 0.f, 0.f}, {0.f, 0.f, 0.f, 0.f}};

  const int swz = (quad ^ (l16 & 7)) * 8;
  const int swz2 = ((quad + 4) ^ (l16 & 7)) * 8;
  const int vswz = (quad ^ (l16 >> 1)) * 8;
  const int vswz2 = ((quad + 4) ^ (l16 >> 1)) * 8;

  const int srl = (lane >> 3);
  const int ktiles = (qblk + 1) * 2;
  const int tmax = 2 * qblk + (wave >> 1);

  {
#pragma unroll
    for (int cc = wave; cc < 8; cc += 4) {
      const int rl = cc * 8 + srl;
      const int ck = ((lane & 7) ^ (rl & 7)) * 8;
      async_load16(&K[base + (size_t)rl * DQ + ck], &Ks[cc * 512]);
      const int cv = ((lane & 7) ^ ((rl >> 1) & 7)) * 8;
      async_load16(&Vt[base + (size_t)rl * LSEQ + cv], &Vs[cc * 512]);
    }
  }
  __syncthreads();

  for (int t = 0; t < ktiles; t++) {
    const int cur = t & 1;
    const int kt = t * 64;
    const bool live = (t <= tmax);

    float km[4];
    if (live) {
#pragma unroll
      for (int ct = 0; ct < 4; ct++) km[ct] = kmask[(size_t)bh * LSEQ + kt + ct * 16 + l16];
    }

    if (t + 1 < ktiles) {
      const int nkt = kt + 64;
      const int nb = (cur ^ 1) * 4096;
#pragma unroll
      for (int cc = wave; cc < 8; cc += 4) {
        const int rl = cc * 8 + srl;
        const int ck = ((lane & 7) ^ (rl & 7)) * 8;
        async_load16(&K[base + (size_t)(nkt + rl) * DQ + ck], &Ks[nb + cc * 512]);
        const int cv = ((lane & 7) ^ ((rl >> 1) & 7)) * 8;
        async_load16(&Vt[base + (size_t)rl * LSEQ + nkt + cv], &Vs[nb + cc * 512]);
      }
    }

    if (live) {
      const unsigned short* Kb = &Ks[cur * 4096];
      const unsigned short* Vb = &Vs[cur * 4096];
      const bool diag = (t == tmax);

#pragma unroll
      for (int sub = 0; sub < 2; sub++) {
        floatx4 s[4];
#pragma unroll
        for (int ct = 0; ct < 4; ct++) {
          const int kr = (ct * 16 + l16) * 64;
          const short8 kf0 = *(const short8*)&Kb[kr + swz];
          const short8 kf1 = *(const short8*)&Kb[kr + swz2];
          floatx4 sv = zf;
          sv = __builtin_amdgcn_mfma_f32_16x16x32_bf16(qf[sub][0], kf0, sv, 0, 0, 0);
          sv = __builtin_amdgcn_mfma_f32_16x16x32_bf16(qf[sub][1], kf1, sv, 0, 0, 0);
          s[ct] = sv;
        }
        const int row0 = qw + sub * 16 + quad * 4;
        unsigned short* pw = &Ps[wave][(sub * 16 + quad * 4) * 72];
        if (diag) {
#pragma unroll
          for (int ct = 0; ct < 4; ct++) {
            const int col = kt + ct * 16 + l16;
#pragma unroll
            for (int r = 0; r < 4; r++) {
              float e = __expf(s[ct][r]) * km[ct];
              e = (col <= row0 + r) ? e : 0.f;
              l_p[sub][r] += e;
              pw[r * 72 + ct * 16 + l16] = f2bf(e);
            }
          }
        } else {
#pragma unroll
          for (int ct = 0; ct < 4; ct++) {
#pragma unroll
            for (int r = 0; r < 4; r++) {
              float e = __expf(s[ct][r]) * km[ct];
              l_p[sub][r] += e;
              pw[r * 72 + ct * 16 + l16] = f2bf(e);
            }
          }
        }
      }
      asm volatile("s_waitcnt lgkmcnt(0)" ::: "memory");

      short8 pf[2][2];
#pragma unroll
      for (int sub = 0; sub < 2; sub++) {
        pf[sub][0] = *(const short8*)&Ps[wave][(sub * 16 + l16) * 72 + quad * 8];
        pf[sub][1] = *(const short8*)&Ps[wave][(sub * 16 + l16) * 72 + 32 + quad * 8];
      }
#pragma unroll
      for (int jj = 0; jj < 4; jj++) {
        const int vr = (jj * 16 + l16) * 64;
        const short8 vf0 = *(const short8*)&Vb[vr + vswz];
        const short8 vf1 = *(const short8*)&Vb[vr + vswz2];
#pragma unroll
        for (int sub = 0; sub < 2; sub++) {
          o[sub][jj] = __builtin_amdgcn_mfma_f32_16x16x32_bf16(pf[sub][0], vf0, o[sub][jj], 0, 0, 0);
          o[sub][jj] = __builtin_amdgcn_mfma_f32_16x16x32_bf16(pf[sub][1], vf1, o[sub][jj], 0, 0, 0);
        }
      }
    }
    __syncthreads();
  }

  const int hd = h * DQ;
#pragma unroll
  for (int sub = 0; sub < 2; sub++)
#pragma unroll
    for (int r = 0; r < 4; r++) {
      float lv = l_p[sub][r];
      lv += __shfl_xor(lv, 1);
      lv += __shfl_xor(lv, 2);
      lv += __shfl_xor(lv, 4);
      lv += __shfl_xor(lv, 8);
      const int row = qw + sub * 16 + quad * 4 + r;
      const float inv = qmask[(size_t)bh * LSEQ + row] / lv;
#pragma unroll
      for (int jj = 0; jj < 4; jj++) {
        const size_t oi = ((size_t)(b * LSEQ + row)) * DM + hd + jj * 16 + l16;
        out[oi] = o[sub][jj][r] * inv + qin[oi];
      }
    }
}

// ---------------- launch ----------------
extern "C" void kernel_launch(void* const* d_in, const int* in_sizes, int n_in,
                              void* d_out, int out_size, void* d_ws, size_t ws_size,
                              hipStream_t stream) {
  const float* q = (const float*)d_in[0];
  const float* k = (const float*)d_in[1];
  const float* Wq = (const float*)d_in[3];
  const float* bq = (const float*)d_in[4];
  const float* Wk = (const float*)d_in[5];
  const float* bk = (const float*)d_in[6];
  const float* Wv = (const float*)d_in[7];
  const float* bv = (const float*)d_in[8];
  float* out = (float*)d_out;

  char* w = (char*)d_ws;
  unsigned short* qb = (unsigned short*)(w + 0);
  unsigned short* kb = (unsigned short*)(w + 16777216);
  unsigned short* Wt = (unsigned short*)(w + 33554432);
  unsigned short* Pq = (unsigned short*)(w + 39845888);
  unsigned short* Pk = (unsigned short*)(w + 56623104);
  unsigned short* Pvt = (unsigned short*)(w + 73400320);
  float* qmask = (float*)(w + 90177536);
  float* kmask = (float*)(w + 90701824);

  convert_qk<<<8192, 256, 0, stream>>>(q, k, qb, kb);
  transpose_w<<<dim3(32, 32, 3), dim3(32, 8), 0, stream>>>(Wq, Wk, Wv, Wt);
  gemm_proj<<<dim3(64, 8, 3), 256, 0, stream>>>(qb, kb, Wt, bq, bk, bv, nullptr,
                                                Pq, Pk, Pvt, qmask, kmask);
  attn_kernel<<<dim3(128, 8), 256, 0, stream>>>(Pq, Pk, Pvt, kmask, qmask, q, out);
}